// Round 1
// baseline (562.657 us; speedup 1.0000x reference)
//
#include <hip/hip_runtime.h>
#include <math.h>

typedef unsigned int u32;
typedef unsigned long long u64;

#define S_N 131072
#define OUT_AT   67108864L
#define OUT_ES   67239936L
#define OUT_SC   67371008L

// workspace float-word offsets
#define W_WCT   0L        // [512][64] combined W^T: cols 0..31 = l2n(new_content) rows, 32..63 = conf_w rows
#define W_NORM2 32768L    // [S] row norm^2 of mem0
#define W_CER   163840L   // [S] conf-side erase partial: sum_j eg_w[32+j]*sigmoid(dot+conf_b[j])
#define W_T4V   294912L   // [2048][32][4] per-block top4 sims values
#define W_T4I   557056L   // [2048][32][4] indices (int)
#define W_ATOM  819200L   // [0] agemax_bits u32, [1] cap_count u32, [2..3] victim_key u64, [4..5] es_key u64, [6] store_sum f32
#define W_FLAG  819208L   // ints: [0] over_cap, [1] victim, [2] should_store, [3] write_idx
#define W_T3V   819216L   // [32][3]
#define W_T3I   819312L   // [32][3] int
#define W_MAXS  819408L   // [32] max_sim per b
#define W_ACT   819440L   // [96] int active flags
#define W_CN    819536L   // [96][512] cand_new
#define W_CO    868688L   // [96][512] cand_old

__device__ __forceinline__ float sigm(float x){ return 1.0f/(1.0f + expf(-x)); }

// ---------------- K0: prep WcT (l2n(new)+conf_w transposed), store-gate MLP, agemax ----------------
__global__ __launch_bounds__(256) void k0(
    const float* __restrict__ nc, const float* __restrict__ query,
    const float* __restrict__ at_in,
    const float* __restrict__ rel_w1, const float* __restrict__ rel_b1,
    const float* __restrict__ rel_g, const float* __restrict__ rel_bb,
    const float* __restrict__ rel_w2, const float* __restrict__ rel_b2,
    const float* __restrict__ nov_w, const float* __restrict__ nov_b,
    const float* __restrict__ gate_w, const float* __restrict__ gate_b,
    const float* __restrict__ conf_w,
    const int* __restrict__ stepp,
    float* __restrict__ ws)
{
  const int bid = blockIdx.x, t = threadIdx.x;
  if (bid < 32) {
    __shared__ float scomb[1024];
    __shared__ float shr[256];
    __shared__ float red[256];
    const float* ncb = nc + bid*512;
    const float* qb  = query + bid*512;
    for (int i=t;i<1024;i+=256) scomb[i] = (i<512)? ncb[i] : qb[i-512];
    __syncthreads();
    float p = scomb[t]*scomb[t] + scomb[t+256]*scomb[t+256];
    red[t]=p; __syncthreads();
    for (int o=128;o>0;o>>=1){ if(t<o) red[t]+=red[t+o]; __syncthreads(); }
    const float denom = fmaxf(sqrtf(red[0]), 1e-12f);
    __syncthreads();
    float* wct = ws + W_WCT;
    wct[(long)t*64 + bid]       = scomb[t]/denom;
    wct[(long)(t+256)*64 + bid] = scomb[t+256]/denom;
    // rel MLP: h1 = combined @ rel_w1^T + b
    const float* w1r = rel_w1 + (long)t*1024;
    float a1 = rel_b1[t];
    for (int k=0;k<1024;k++) a1 += scomb[k]*w1r[k];
    red[t]=a1; __syncthreads();
    for (int o=128;o>0;o>>=1){ if(t<o) red[t]+=red[t+o]; __syncthreads(); }
    const float mean = red[0]/256.0f;
    __syncthreads();
    const float dd = a1-mean;
    red[t]=dd*dd; __syncthreads();
    for (int o=128;o>0;o>>=1){ if(t<o) red[t]+=red[t+o]; __syncthreads(); }
    const float var = red[0]/256.0f;
    __syncthreads();
    const float xh = (a1-mean)/sqrtf(var+1e-5f);
    shr[t] = fmaxf(xh*rel_g[t]+rel_bb[t], 0.0f);
    __syncthreads();
    float gp = 0.0f;
    if (t<128){
      const float* w2r = rel_w2 + (long)t*256;
      float a2 = rel_b2[t];
      for (int k=0;k<256;k++) a2 += shr[k]*w2r[k];
      const float relv = fmaxf(a2,0.0f);
      const float* nwr = nov_w + (long)t*512;
      float a3 = nov_b[t];
      for (int k=0;k<512;k++) a3 += scomb[k]*nwr[k];
      gp = (relv + sigm(a3))*gate_w[t];
    }
    red[t]=gp; __syncthreads();
    for (int o=128;o>0;o>>=1){ if(t<o) red[t]+=red[t+o]; __syncthreads(); }
    if (t==0) atomicAdd((float*)(ws+W_ATOM+6), sigm(red[0]+gate_b[0]));
  } else if (bid < 64) {
    const int j = bid-32;
    float* wct = ws + W_WCT;
    for (int k=t;k<512;k+=256) wct[(long)k*64 + 32 + j] = conf_w[j*512+k];
  } else {
    __shared__ float red[256];
    const float step = (float)(*stepp);
    const int per = (S_N + 191)/192;
    const int base = (bid-64)*per;
    const int end = min(base+per, S_N);
    float m = 0.0f;
    for (int s=base+t; s<end; s+=256) m = fmaxf(m, fmaxf(step - at_in[s], 0.0f));
    red[t]=m; __syncthreads();
    for (int o=128;o>0;o>>=1){ if(t<o) red[t]=fmaxf(red[t],red[t+o]); __syncthreads(); }
    if (t==0) atomicMax((u32*)(ws+W_ATOM+0), __float_as_uint(red[0]));
  }
}

// ---------------- K1: fused copy + norms + sims top4 + conf erase partials ----------------
__global__ __launch_bounds__(256) void k1(
    const float* __restrict__ mem,
    const float* __restrict__ conf_b, const float* __restrict__ eg_w,
    float* __restrict__ out, float* __restrict__ ws)
{
  __shared__ float lx[64][68];
  __shared__ float lw[64][68];
  __shared__ float ssim[64][33];
  __shared__ float snorm[64];
  const int t = threadIdx.x, bid = blockIdx.x;
  const long rowbase = (long)bid*64;
  const int lane = t & 63, wid = t >> 6;
  const int lr = lane & 15, lj = lane >> 4;
  const int myrow = wid*16 + lr;
  const int hr = t >> 4;          // 0..15
  const int c4 = (t & 15)*4;      // 0..60
  const float* wct = ws + W_WCT;
  float acc[16];
  #pragma unroll
  for (int i=0;i<16;i++) acc[i]=0.0f;
  float normp[4] = {0.0f,0.0f,0.0f,0.0f};
  for (int ch=0; ch<8; ++ch) {
    #pragma unroll
    for (int it=0; it<4; ++it) {
      const int r = 16*it + hr;
      const long g = (rowbase + r)*512 + ch*64 + c4;
      float4 v = *(const float4*)(mem + g);
      *(float4*)(out + g) = v;                 // fused copy to output
      *(float4*)&lx[r][c4] = v;
      normp[it] += v.x*v.x + v.y*v.y + v.z*v.z + v.w*v.w;
    }
    #pragma unroll
    for (int it=0; it<4; ++it) {
      const int k = 16*it + hr;
      float4 v = *(const float4*)(wct + (long)(ch*64 + k)*64 + c4);
      *(float4*)&lw[k][c4] = v;
    }
    __syncthreads();
    #pragma unroll 2
    for (int k=0;k<64;k+=4) {
      float4 xv = *(const float4*)&lx[myrow][k];
      float xs[4] = {xv.x, xv.y, xv.z, xv.w};
      #pragma unroll
      for (int kk=0;kk<4;kk++) {
        #pragma unroll
        for (int q=0;q<4;q++) {
          float4 wv = *(const float4*)&lw[k+kk][lj*16+4*q];
          acc[4*q+0] += xs[kk]*wv.x;
          acc[4*q+1] += xs[kk]*wv.y;
          acc[4*q+2] += xs[kk]*wv.z;
          acc[4*q+3] += xs[kk]*wv.w;
        }
      }
    }
    __syncthreads();
  }
  // per-row norm^2: 16 threads (same t>>4) share a row; reduce within 16-lane groups
  #pragma unroll
  for (int it=0; it<4; ++it) {
    float v = normp[it];
    v += __shfl_xor(v,8); v += __shfl_xor(v,4); v += __shfl_xor(v,2); v += __shfl_xor(v,1);
    if ((lane & 15)==0) snorm[16*it + hr] = v;
  }
  __syncthreads();
  const float n2my = snorm[myrow];
  const float inv = 1.0f / fmaxf(sqrtf(n2my), 1e-12f);
  if (lj < 2) {
    #pragma unroll
    for (int m=0;m<16;m++) ssim[myrow][lj*16+m] = acc[m]*inv;
  } else {
    float part = 0.0f;
    #pragma unroll
    for (int m=0;m<16;m++) {
      const int j = (lj-2)*16+m;
      part += eg_w[32+j]*sigm(acc[m]+conf_b[j]);
    }
    part += __shfl_xor(part,16);
    if (lj==2) (ws+W_CER)[rowbase + myrow] = part;
  }
  if (t<64) (ws+W_NORM2)[rowbase + t] = snorm[t];
  __syncthreads();
  if (t==0) {
    u32 c=0;
    for (int r=0;r<64;r++) c += (sqrtf(snorm[r]) > 0.5f)?1u:0u;
    atomicAdd((u32*)(ws+W_ATOM+1), c);
  }
  if (t<32) {
    // per-block top-4 (value desc, earlier row wins ties via strict > on ascending scan)
    float v0=-2,v1=-2,v2=-2,v3=-2; int i0=0,i1=0,i2=0,i3=0;
    for (int r=0;r<64;r++){
      const float v = ssim[r][t]; const int gi = (int)rowbase + r;
      if (v > v2) {
        if (v > v0)      { v3=v2;i3=i2; v2=v1;i2=i1; v1=v0;i1=i0; v0=v;i0=gi; }
        else if (v > v1) { v3=v2;i3=i2; v2=v1;i2=i1; v1=v;i1=gi; }
        else             { v3=v2;i3=i2; v2=v;i2=gi; }
      } else if (v > v3) { v3=v;i3=gi; }
    }
    float* t4v = ws + W_T4V + (long)bid*128 + t*4;
    int*   t4i = (int*)(ws + W_T4I) + (long)bid*128 + t*4;
    t4v[0]=v0; t4v[1]=v1; t4v[2]=v2; t4v[3]=v3;
    t4i[0]=i0; t4i[1]=i1; t4i[2]=i2; t4i[3]=i3;
  }
}

// ---------------- Kv2: capacity flag + victim argmax ----------------
__global__ __launch_bounds__(256) void kv2(
    const float* __restrict__ at_in, const int* __restrict__ stepp,
    float* __restrict__ ws, float* __restrict__ out)
{
  __shared__ u64 red[256];
  const int t = threadIdx.x, bid = blockIdx.x;
  if (bid==0 && t==0) {
    const u32 cnt = *(u32*)(ws+W_ATOM+1);
    const float cap = (float)cnt / (float)S_N;
    out[OUT_SC+3] = cap;
    ((int*)(ws+W_FLAG))[0] = (cap > 0.85f) ? 1 : 0;
  }
  const float step = (float)(*stepp);
  const float agemax = __uint_as_float(*(u32*)(ws+W_ATOM+0));
  const float dnm = agemax + 1e-6f;
  const float* n2 = ws+W_NORM2;
  const int base = bid*512;
  u64 best = 0;
  #pragma unroll
  for (int i=0;i<2;i++) {
    const int s = base + t + i*256;
    const float age = fmaxf(step - at_in[s], 0.0f);
    const float q = age/dnm;
    const float nr = sqrtf(n2[s]);
    const float sc = q + (1.0f - sigm(nr));
    const u64 key = ((u64)__float_as_uint(sc)<<32) | (u64)(0xFFFFFFFFu - (u32)s);
    best = (key>best)?key:best;
  }
  red[t]=best; __syncthreads();
  for (int o=128;o>0;o>>=1){ if(t<o){ u64 a=red[t],b2=red[t+o]; red[t]=(a>b2)?a:b2; } __syncthreads(); }
  if (t==0) atomicMax((u64*)(ws+W_ATOM+2), red[0]);
}

// ---------------- K3: at copy + erase_scores + es argmax ----------------
__global__ __launch_bounds__(256) void k3(
    const float* __restrict__ at_in, const int* __restrict__ stepp,
    const float* __restrict__ lru_w, const float* __restrict__ lru_b,
    const float* __restrict__ eg_w, const float* __restrict__ eg_b,
    const float* __restrict__ conf_b,
    float* __restrict__ ws, float* __restrict__ out)
{
  __shared__ u64 red[256];
  const int t=threadIdx.x, bid=blockIdx.x;
  const u64 vk = *(u64*)(ws+W_ATOM+2);
  const int victim = (int)(0xFFFFFFFFu - (u32)(vk & 0xFFFFFFFFull));
  const int oc = ((int*)(ws+W_FLAG))[0];
  if (bid==0 && t==0) ((int*)(ws+W_FLAG))[1] = victim;
  const float step = (float)(*stepp);
  float* at_out = out + OUT_AT;
  float* es_out = out + OUT_ES;
  const float* cer = ws+W_CER;
  u64 best=0;
  const int base=bid*512;
  for (int i=0;i<2;i++){
    const int s = base + t + i*256;
    const float a = at_in[s];
    const bool isv = oc && (s==victim);
    const float av = isv ? -99999.0f : a;
    at_out[s] = av;
    const float x = (step - av)/1000.0f;
    float lsum = 0.0f;
    #pragma unroll
    for (int j=0;j<32;j++) lsum += eg_w[j]*fmaxf(lru_w[j]*x + lru_b[j], 0.0f);
    float ce;
    if (isv) { ce=0.0f; for (int j=0;j<32;j++) ce += eg_w[32+j]*sigm(conf_b[j]); }
    else ce = cer[s];
    const float es = sigm(lsum + ce + eg_b[0]);
    es_out[s] = es;
    const u64 key = ((u64)__float_as_uint(es)<<32) | (u64)(0xFFFFFFFFu - (u32)s);
    best = (key>best)?key:best;
  }
  red[t]=best; __syncthreads();
  for (int o=128;o>0;o>>=1){ if(t<o){ u64 a=red[t],b2=red[t+o]; red[t]=(a>b2)?a:b2; } __syncthreads(); }
  if (t==0) atomicMax((u64*)(ws+W_ATOM+4), red[0]);
}

// ---------------- K2b: merge per-block top4 -> global top3 of sims2, max_sim per b ----------------
__device__ __forceinline__ void ins3(float v, int idx, float* V, int* I){
  if ( (v>V[0]) || (v==V[0] && idx<I[0]) ) { V[2]=V[1];I[2]=I[1]; V[1]=V[0];I[1]=I[0]; V[0]=v;I[0]=idx; }
  else if ( (v>V[1]) || (v==V[1] && idx<I[1]) ) { V[2]=V[1];I[2]=I[1]; V[1]=v;I[1]=idx; }
  else if ( (v>V[2]) || (v==V[2] && idx<I[2]) ) { V[2]=v;I[2]=idx; }
}

__global__ __launch_bounds__(256) void k2b(float* __restrict__ ws)
{
  __shared__ float lv[768];
  __shared__ int   li[768];
  __shared__ float lm[256];
  const int b = blockIdx.x, t = threadIdx.x;
  const int oc = ((int*)(ws+W_FLAG))[0];
  const int victim = ((int*)(ws+W_FLAG))[1];
  const float* t4v = ws + W_T4V;
  const int* t4i = (const int*)(ws + W_T4I);
  float V[3] = {-2,-2,-2}; int I[3] = {0,0,0};
  float mx = -2.0f;
  for (int c=t; c<8192; c+=256) {
    const long o = (long)(c>>2)*128 + b*4 + (c&3);
    const float v = t4v[o];
    const int idx = t4i[o];
    if ((c&3)==0) mx = fmaxf(mx, v);        // max_sim uses pre-erase sims incl. victim
    if (oc && idx==victim) continue;        // post-erase sims2: victim row becomes 0
    ins3(v, idx, V, I);
  }
  lv[t*3]=V[0]; lv[t*3+1]=V[1]; lv[t*3+2]=V[2];
  li[t*3]=I[0]; li[t*3+1]=I[1]; li[t*3+2]=I[2];
  lm[t]=mx;
  __syncthreads();
  if (t==0) {
    float FV[3]={-2,-2,-2}; int FI[3]={0,0,0};
    for (int c=0;c<768;c++) ins3(lv[c], li[c], FV, FI);
    if (oc) ins3(0.0f, victim, FV, FI);     // sims2[b][victim] == 0 exactly
    float M=-2.0f;
    for (int c=0;c<256;c++) M = fmaxf(M, lm[c]);
    for (int p=0;p<3;p++){ (ws+W_T3V)[b*3+p]=FV[p]; ((int*)(ws+W_T3I))[b*3+p]=FI[p]; }
    (ws+W_MAXS)[b]=M;
  }
}

// ---------------- K4: drift-detect/strength MLPs + candidates; block 96 = scalar stats/flags ----------------
__global__ __launch_bounds__(256) void k4(
    const float* __restrict__ mem, const float* __restrict__ nc,
    const float* __restrict__ dd_w1, const float* __restrict__ dd_b1,
    const float* __restrict__ dd_w2, const float* __restrict__ dd_b2,
    const float* __restrict__ ds_w1, const float* __restrict__ ds_b1,
    const float* __restrict__ ds_w2, const float* __restrict__ ds_b2,
    float* __restrict__ ws, float* __restrict__ out)
{
  const int bid = blockIdx.x, t = threadIdx.x;
  const int oc = ((int*)(ws+W_FLAG))[0];
  const int victim = ((int*)(ws+W_FLAG))[1];
  if (bid == 96) {
    if (t==0) {
      const float sm = (ws+W_ATOM)[6] / 32.0f;
      float nsum=0.0f, rsum=0.0f, csum=0.0f;
      for (int b2=0;b2<32;b2++){
        const float ms = (ws+W_MAXS)[b2];
        nsum += (1.0f-ms)/2.0f;
        rsum += sigm(ms);
      }
      for (int c=0;c<96;c++){
        const float v=(ws+W_T3V)[c];
        if (v>0.7f && v<0.99f) csum += 1.0f;
      }
      const float novm = nsum/32.0f;
      out[OUT_SC+0]=sm;
      out[OUT_SC+1]=novm;
      out[OUT_SC+2]=rsum/32.0f;
      out[OUT_SC+4]=csum;
      ((int*)(ws+W_FLAG))[2] = (sm>0.35f && novm>0.4f) ? 1 : 0;
      const u64 ek = *(u64*)(ws+W_ATOM+4);
      const int esidx = (int)(0xFFFFFFFFu - (u32)(ek & 0xFFFFFFFFull));
      ((int*)(ws+W_FLAG))[3] = oc ? victim : esidx;
    }
    return;
  }
  __shared__ float sp[1024];
  __shared__ float sh[256];
  __shared__ float red[256];
  const int b = bid/3;
  const int oi = ((int*)(ws+W_T3I))[bid];
  const float tv = (ws+W_T3V)[bid];
  const bool zold = oc && (oi==victim);   // gather from post-erase mem
  for (int i=t;i<1024;i+=256)
    sp[i] = (i<512) ? nc[b*512+i] : (zold ? 0.0f : mem[(long)oi*512 + (i-512)]);
  __syncthreads();
  {
    const float* wr = dd_w1 + (long)t*1024;
    float a = dd_b1[t];
    for (int k=0;k<1024;k++) a += sp[k]*wr[k];
    sh[t]=fmaxf(a,0.0f);
  }
  __syncthreads();
  red[t]=sh[t]*dd_w2[t]; __syncthreads();
  for (int o=128;o>0;o>>=1){ if(t<o) red[t]+=red[t+o]; __syncthreads(); }
  const float prob = sigm(red[0]+dd_b2[0]);
  __syncthreads();
  {
    const float* wr = ds_w1 + (long)t*1024;
    float a = ds_b1[t];
    for (int k=0;k<1024;k++) a += sp[k]*wr[k];
    sh[t]=fmaxf(a,0.0f);
  }
  __syncthreads();
  red[t]=sh[t]*ds_w2[t]; __syncthreads();
  for (int o=128;o>0;o>>=1){ if(t<o) red[t]+=red[t+o]; __syncthreads(); }
  const float sstr = sigm(red[0]+ds_b2[0]);
  if (t==0) ((int*)(ws+W_ACT))[bid] = ((tv>0.7f) && (tv<0.99f) && (prob>0.5f)) ? 1 : 0;
  for (int k=t;k<512;k+=256){
    const float nw=sp[k], od=sp[512+k];
    const float avg=(nw+od)/2.0f;
    (ws+W_CN)[(long)bid*512+k] = (1.0f-sstr)*nw + sstr*avg;
    (ws+W_CO)[(long)bid*512+k] = (1.0f-sstr)*od + sstr*avg;
  }
}

// ---------------- K5: sequential finale (erase, drift scatter, store, change/ema/decay) ----------------
__global__ __launch_bounds__(256) void k5(
    const float* __restrict__ mem, const float* __restrict__ nc,
    const float* __restrict__ decay_in, const float* __restrict__ ema_in,
    const int* __restrict__ stepp,
    float* __restrict__ ws, float* __restrict__ out)
{
  __shared__ int rows[256];
  __shared__ int nrows_s;
  __shared__ float red[256];
  const int t=threadIdx.x;
  const int oc=((int*)(ws+W_FLAG))[0];
  const int victim=((int*)(ws+W_FLAG))[1];
  const int should=((int*)(ws+W_FLAG))[2];
  const int widx=((int*)(ws+W_FLAG))[3];
  const int* act=(const int*)(ws+W_ACT);
  const int* t3i=(const int*)(ws+W_T3I);
  const float step=(float)(*stepp);
  float* at_out = out+OUT_AT;
  // 1. emergency erase (at[victim] already fixed by k3)
  if (oc) { for (int k=t;k<512;k+=256) out[(long)victim*512+k]=0.0f; }
  __threadfence(); __syncthreads();
  // 2. sequential masked drift scatter (later i overwrites same row; same thread writes same k -> ordered)
  for (int i=0;i<96;i++){
    if (act[i]) {
      const long s=t3i[i];
      for (int k=t;k<512;k+=256) out[s*512+k]=(ws+W_CO)[(long)i*512+k];
    }
  }
  int dn_src=-1;
  for (int i=0;i<3;i++) if (act[i]) dn_src=i;   // drifted_new[0] = last active of b==0
  __threadfence(); __syncthreads();
  // 3. conditional store
  if (should) {
    for (int k=t;k<512;k+=256)
      out[(long)widx*512+k] = (dn_src>=0)? (ws+W_CN)[(long)dn_src*512+k] : nc[k];
    if (t==0) at_out[widx]=step;
  }
  __threadfence(); __syncthreads();
  // 4. change = mean |mem_final - mem0| : only changed rows contribute
  if (t==0){
    int n=0;
    if (oc) rows[n++]=victim;
    for (int i=0;i<96;i++) if (act[i]) {
      const int s=t3i[i]; bool dup=false;
      for (int j=0;j<n;j++) if (rows[j]==s) dup=true;
      if (!dup) rows[n++]=s;
    }
    if (should) {
      bool dup=false;
      for (int j=0;j<n;j++) if (rows[j]==widx) dup=true;
      if (!dup) rows[n++]=widx;
    }
    nrows_s=n;
  }
  __syncthreads();
  float part=0.0f;
  for (int ri=0;ri<nrows_s;ri++){
    const long base=(long)rows[ri]*512;
    for (int k=t;k<512;k+=256) part += fabsf(out[base+k]-mem[base+k]);
  }
  red[t]=part; __syncthreads();
  for (int o=128;o>0;o>>=1){ if(t<o) red[t]+=red[t+o]; __syncthreads(); }
  if (t==0){
    const float change = red[0]/67108864.0f;
    const float ema = 0.9f*ema_in[0] + 0.1f*change;
    const float adj = (ema>0.1f)? -0.005f : 0.005f;
    const float dec = fminf(fmaxf(decay_in[0]+adj,0.01f),0.2f);
    out[OUT_SC+5]=dec;
    out[OUT_SC+6]=ema;
  }
}

extern "C" void kernel_launch(void* const* d_in, const int* in_sizes, int n_in,
                              void* d_out, int out_size, void* d_ws, size_t ws_size,
                              hipStream_t stream) {
  const float* nc     = (const float*)d_in[0];
  const float* query  = (const float*)d_in[1];
  const float* mem    = (const float*)d_in[2];
  const float* at_in  = (const float*)d_in[3];
  const float* rel_w1 = (const float*)d_in[4];
  const float* rel_b1 = (const float*)d_in[5];
  const float* rel_g  = (const float*)d_in[6];
  const float* rel_bb = (const float*)d_in[7];
  const float* rel_w2 = (const float*)d_in[8];
  const float* rel_b2 = (const float*)d_in[9];
  const float* nov_w  = (const float*)d_in[10];
  const float* nov_b  = (const float*)d_in[11];
  const float* gate_w = (const float*)d_in[12];
  const float* gate_b = (const float*)d_in[13];
  const float* lru_w  = (const float*)d_in[14];
  const float* lru_b  = (const float*)d_in[15];
  const float* conf_w = (const float*)d_in[16];
  const float* conf_b = (const float*)d_in[17];
  const float* eg_w   = (const float*)d_in[18];
  const float* eg_b   = (const float*)d_in[19];
  const float* dd_w1  = (const float*)d_in[20];
  const float* dd_b1  = (const float*)d_in[21];
  const float* dd_w2  = (const float*)d_in[22];
  const float* dd_b2  = (const float*)d_in[23];
  const float* ds_w1  = (const float*)d_in[24];
  const float* ds_b1  = (const float*)d_in[25];
  const float* ds_w2  = (const float*)d_in[26];
  const float* ds_b2  = (const float*)d_in[27];
  const float* decay  = (const float*)d_in[28];
  const float* ema    = (const float*)d_in[29];
  const int*   stepp  = (const int*)d_in[30];
  float* out = (float*)d_out;
  float* ws  = (float*)d_ws;

  // zero the atomic scratch (ws is poisoned 0xAA and never re-poisoned between replays)
  hipMemsetAsync((char*)d_ws + (size_t)W_ATOM*4, 0, 32, stream);

  k0 <<<dim3(256), dim3(256), 0, stream>>>(nc, query, at_in, rel_w1, rel_b1, rel_g, rel_bb,
                                           rel_w2, rel_b2, nov_w, nov_b, gate_w, gate_b,
                                           conf_w, stepp, ws);
  k1 <<<dim3(2048), dim3(256), 0, stream>>>(mem, conf_b, eg_w, out, ws);
  kv2<<<dim3(256), dim3(256), 0, stream>>>(at_in, stepp, ws, out);
  k3 <<<dim3(256), dim3(256), 0, stream>>>(at_in, stepp, lru_w, lru_b, eg_w, eg_b, conf_b, ws, out);
  k2b<<<dim3(32),  dim3(256), 0, stream>>>(ws);
  k4 <<<dim3(97),  dim3(256), 0, stream>>>(mem, nc, dd_w1, dd_b1, dd_w2, dd_b2,
                                           ds_w1, ds_b1, ds_w2, ds_b2, ws, out);
  k5 <<<dim3(1),   dim3(256), 0, stream>>>(mem, nc, decay, ema, stepp, ws, out);
}

// Round 2
// 414.224 us; speedup vs baseline: 1.3583x; 1.3583x over previous
//
#include <hip/hip_runtime.h>
#include <math.h>

typedef unsigned int u32;
typedef unsigned long long u64;

#define S_N 131072
#define OUT_AT   67108864L
#define OUT_ES   67239936L
#define OUT_SC   67371008L

// workspace float-word offsets
#define W_WCT   0L        // [512][64] combined W^T: cols 0..31 = l2n(new_content) rows, 32..63 = conf_w rows
#define W_NORM2 32768L    // [S] row norm^2 of mem0
#define W_CER   163840L   // [S] conf-side erase partial
#define W_T4V   294912L   // [32][2048][4] per-block top4 sims values (b-major, coalesced reader)
#define W_T4I   557056L   // [32][2048][4] indices (int)
#define W_ATOM  819200L   // [0] agemax_bits u32, [1] cap_count u32, [2..3] victim_key u64, [4..5] es_key u64, [6] store_sum f32
#define W_FLAG  819208L   // ints: [0] over_cap, [1] victim, [2] should_store, [3] write_idx
#define W_T3V   819216L   // [32][3]
#define W_T3I   819312L   // [32][3] int
#define W_MAXS  819408L   // [32] max_sim per b
#define W_ACT   819440L   // [96] int active flags
#define W_CN    819536L   // [96][512] cand_new
#define W_CO    868688L   // [96][512] cand_old

__device__ __forceinline__ float sigm(float x){ return 1.0f/(1.0f + expf(-x)); }

// ---------------- K0: prep WcT (l2n(new)+conf_w transposed), store-gate MLP, agemax ----------------
__global__ __launch_bounds__(256) void k0(
    const float* __restrict__ nc, const float* __restrict__ query,
    const float* __restrict__ at_in,
    const float* __restrict__ rel_w1, const float* __restrict__ rel_b1,
    const float* __restrict__ rel_g, const float* __restrict__ rel_bb,
    const float* __restrict__ rel_w2, const float* __restrict__ rel_b2,
    const float* __restrict__ nov_w, const float* __restrict__ nov_b,
    const float* __restrict__ gate_w, const float* __restrict__ gate_b,
    const float* __restrict__ conf_w,
    const int* __restrict__ stepp,
    float* __restrict__ ws)
{
  const int bid = blockIdx.x, t = threadIdx.x;
  if (bid < 32) {
    __shared__ __align__(16) float scomb[1024];
    __shared__ __align__(16) float shr[256];
    __shared__ float red[256];
    const float* ncb = nc + bid*512;
    const float* qb  = query + bid*512;
    for (int i=t;i<1024;i+=256) scomb[i] = (i<512)? ncb[i] : qb[i-512];
    __syncthreads();
    float p = scomb[t]*scomb[t] + scomb[t+256]*scomb[t+256];
    red[t]=p; __syncthreads();
    for (int o=128;o>0;o>>=1){ if(t<o) red[t]+=red[t+o]; __syncthreads(); }
    const float denom = fmaxf(sqrtf(red[0]), 1e-12f);
    __syncthreads();
    float* wct = ws + W_WCT;
    wct[(long)t*64 + bid]       = scomb[t]/denom;
    wct[(long)(t+256)*64 + bid] = scomb[t+256]/denom;
    // rel MLP: h1 = combined @ rel_w1^T + b  (float4 loads; L1 line reuse across k)
    const float4* w1r = (const float4*)(rel_w1 + (long)t*1024);
    const float4* sc4 = (const float4*)scomb;
    float a1 = rel_b1[t];
    #pragma unroll 4
    for (int k=0;k<256;k++){ float4 w=w1r[k], s=sc4[k]; a1 += w.x*s.x+w.y*s.y+w.z*s.z+w.w*s.w; }
    red[t]=a1; __syncthreads();
    for (int o=128;o>0;o>>=1){ if(t<o) red[t]+=red[t+o]; __syncthreads(); }
    const float mean = red[0]/256.0f;
    __syncthreads();
    const float dd = a1-mean;
    red[t]=dd*dd; __syncthreads();
    for (int o=128;o>0;o>>=1){ if(t<o) red[t]+=red[t+o]; __syncthreads(); }
    const float var = red[0]/256.0f;
    __syncthreads();
    const float xh = (a1-mean)/sqrtf(var+1e-5f);
    shr[t] = fmaxf(xh*rel_g[t]+rel_bb[t], 0.0f);
    __syncthreads();
    float gp = 0.0f;
    if (t<128){
      const float4* w2r = (const float4*)(rel_w2 + (long)t*256);
      const float4* sh4 = (const float4*)shr;
      float a2 = rel_b2[t];
      #pragma unroll 4
      for (int k=0;k<64;k++){ float4 w=w2r[k], s=sh4[k]; a2 += w.x*s.x+w.y*s.y+w.z*s.z+w.w*s.w; }
      const float relv = fmaxf(a2,0.0f);
      const float4* nwr = (const float4*)(nov_w + (long)t*512);
      float a3 = nov_b[t];
      #pragma unroll 4
      for (int k=0;k<128;k++){ float4 w=nwr[k], s=sc4[k]; a3 += w.x*s.x+w.y*s.y+w.z*s.z+w.w*s.w; }
      gp = (relv + sigm(a3))*gate_w[t];
    }
    red[t]=gp; __syncthreads();
    for (int o=128;o>0;o>>=1){ if(t<o) red[t]+=red[t+o]; __syncthreads(); }
    if (t==0) atomicAdd((float*)(ws+W_ATOM+6), sigm(red[0]+gate_b[0]));
  } else if (bid < 64) {
    const int j = bid-32;
    float* wct = ws + W_WCT;
    for (int k=t;k<512;k+=256) wct[(long)k*64 + 32 + j] = conf_w[j*512+k];
  } else {
    __shared__ float red[256];
    const float step = (float)(*stepp);
    const int per = (S_N + 191)/192;
    const int base = (bid-64)*per;
    const int end = min(base+per, S_N);
    float m = 0.0f;
    for (int s=base+t; s<end; s+=256) m = fmaxf(m, fmaxf(step - at_in[s], 0.0f));
    red[t]=m; __syncthreads();
    for (int o=128;o>0;o>>=1){ if(t<o) red[t]=fmaxf(red[t],red[t+o]); __syncthreads(); }
    if (t==0) atomicMax((u32*)(ws+W_ATOM+0), __float_as_uint(red[0]));
  }
}

// ---------------- K1: fused copy + norms + sims top4 + conf erase partials ----------------
// 64-row tile. Threads: q = t&3 (K-split over chunk), c16 = (t>>2)&3 (16-col group),
// r4 = t>>4 (4-row group). acc[4][16] per thread; q-partials reduced via shfl_xor(1,2).
__global__ __launch_bounds__(256,3) void k1(
    const float* __restrict__ mem,
    const float* __restrict__ conf_b, const float* __restrict__ eg_w,
    float* __restrict__ out, float* __restrict__ ws)
{
  __shared__ __align__(16) float lx[64*68];    // row stride 68, float4-col XOR-swizzled by (row>>2)&3
  __shared__ __align__(16) float lw[16*276];   // [k&15][(k>>4)*68 + col]
  __shared__ float ssim[64][33];
  __shared__ float snorm[64];
  const int t = threadIdx.x, bid = blockIdx.x;
  const long rowbase = (long)bid*64;
  const int lane = t & 63;
  // staging ids
  const int hr = t >> 4;          // 0..15
  const int cj = t & 15;          // float4 col
  const int c4 = cj*4;
  // compute ids
  const int q = t & 3, c16 = (t>>2)&3, r4 = t>>4;
  const int swz = r4 & 3;
  const float* wct = ws + W_WCT;
  float acc[4][16];
  #pragma unroll
  for (int i=0;i<4;i++){
    #pragma unroll
    for (int m=0;m<16;m++) acc[i][m]=0.0f;
  }
  float normp[4] = {0.0f,0.0f,0.0f,0.0f};
  #pragma unroll 1
  for (int ch=0; ch<8; ++ch) {
    // stage x tile (+ fused copy to out)
    #pragma unroll
    for (int it=0; it<4; ++it) {
      const int r = 16*it + hr;
      const long g = (rowbase + r)*512 + ch*64 + c4;
      float4 v = *(const float4*)(mem + g);
      *(float4*)(out + g) = v;
      const int cjs = cj ^ ((r>>2)&3);
      *(float4*)&lx[r*68 + cjs*4] = v;
      normp[it] += v.x*v.x + v.y*v.y + v.z*v.z + v.w*v.w;
    }
    // stage w tile: chunk-local k = 16*it + hr  ->  lw[hr][it*68 + c4]
    #pragma unroll
    for (int it=0; it<4; ++it) {
      float4 v = *(const float4*)(wct + (long)(ch*64 + 16*it + hr)*64 + c4);
      *(float4*)&lw[hr*276 + it*68 + c4] = v;
    }
    __syncthreads();
    // compute: this thread handles chunk-local k in [q*16, q*16+16)
    #pragma unroll
    for (int kk4=0; kk4<4; ++kk4) {
      float xa[4][4];
      #pragma unroll
      for (int i=0;i<4;i++){
        float4 v = *(const float4*)&lx[(r4*4+i)*68 + (((q*4+kk4)^swz)*4)];
        xa[i][0]=v.x; xa[i][1]=v.y; xa[i][2]=v.z; xa[i][3]=v.w;
      }
      #pragma unroll
      for (int e=0;e<4;e++){
        const float* wp = &lw[(kk4*4+e)*276 + q*68 + c16*16];
        float4 w0 = *(const float4*)(wp);
        float4 w1 = *(const float4*)(wp+4);
        float4 w2 = *(const float4*)(wp+8);
        float4 w3 = *(const float4*)(wp+12);
        #pragma unroll
        for (int i=0;i<4;i++){
          const float xs = xa[i][e];
          acc[i][0]+=xs*w0.x; acc[i][1]+=xs*w0.y; acc[i][2]+=xs*w0.z; acc[i][3]+=xs*w0.w;
          acc[i][4]+=xs*w1.x; acc[i][5]+=xs*w1.y; acc[i][6]+=xs*w1.z; acc[i][7]+=xs*w1.w;
          acc[i][8]+=xs*w2.x; acc[i][9]+=xs*w2.y; acc[i][10]+=xs*w2.z; acc[i][11]+=xs*w2.w;
          acc[i][12]+=xs*w3.x; acc[i][13]+=xs*w3.y; acc[i][14]+=xs*w3.z; acc[i][15]+=xs*w3.w;
        }
      }
    }
    __syncthreads();
  }
  // per-row norm^2 reduce within 16-lane groups
  #pragma unroll
  for (int it=0; it<4; ++it) {
    float v = normp[it];
    v += __shfl_xor(v,8); v += __shfl_xor(v,4); v += __shfl_xor(v,2); v += __shfl_xor(v,1);
    if ((lane & 15)==0) snorm[16*it + hr] = v;
  }
  __syncthreads();
  // reduce acc over the 4 K-split lanes (lane bits 0,1)
  #pragma unroll
  for (int i=0;i<4;i++){
    #pragma unroll
    for (int m=0;m<16;m++){
      float v = acc[i][m];
      v += __shfl_xor(v,1);
      v += __shfl_xor(v,2);
      acc[i][m]=v;
    }
  }
  if (q==0){
    if (c16<2){
      #pragma unroll
      for (int i=0;i<4;i++){
        const int R = r4*4+i;
        const float inv = 1.0f/fmaxf(sqrtf(snorm[R]),1e-12f);
        #pragma unroll
        for (int m=0;m<16;m++) ssim[R][c16*16+m] = acc[i][m]*inv;
      }
    } else {
      #pragma unroll
      for (int i=0;i<4;i++){
        float part=0.0f;
        #pragma unroll
        for (int m=0;m<16;m++){
          const int j=(c16-2)*16+m;
          part += eg_w[32+j]*sigm(acc[i][m]+conf_b[j]);
        }
        part += __shfl_xor(part,4);
        if (c16==2) (ws+W_CER)[rowbase + r4*4+i]=part;
      }
    }
  }
  if (t<64) (ws+W_NORM2)[rowbase + t] = snorm[t];
  __syncthreads();
  if (t==0) {
    u32 c=0;
    for (int r=0;r<64;r++) c += (sqrtf(snorm[r]) > 0.5f)?1u:0u;
    atomicAdd((u32*)(ws+W_ATOM+1), c);
  }
  if (t<32) {
    float v0=-2,v1=-2,v2=-2,v3=-2; int i0=0,i1=0,i2=0,i3=0;
    for (int r=0;r<64;r++){
      const float v = ssim[r][t]; const int gi = (int)rowbase + r;
      if (v > v2) {
        if (v > v0)      { v3=v2;i3=i2; v2=v1;i2=i1; v1=v0;i1=i0; v0=v;i0=gi; }
        else if (v > v1) { v3=v2;i3=i2; v2=v1;i2=i1; v1=v;i1=gi; }
        else             { v3=v2;i3=i2; v2=v;i2=gi; }
      } else if (v > v3) { v3=v;i3=gi; }
    }
    float* t4v = ws + W_T4V + (long)t*8192 + bid*4;     // [32][2048][4]
    int*   t4i = (int*)(ws + W_T4I) + (long)t*8192 + bid*4;
    t4v[0]=v0; t4v[1]=v1; t4v[2]=v2; t4v[3]=v3;
    t4i[0]=i0; t4i[1]=i1; t4i[2]=i2; t4i[3]=i3;
  }
}

// ---------------- Kv2: capacity flag + victim argmax ----------------
__global__ __launch_bounds__(256) void kv2(
    const float* __restrict__ at_in, const int* __restrict__ stepp,
    float* __restrict__ ws, float* __restrict__ out)
{
  __shared__ u64 red[256];
  const int t = threadIdx.x, bid = blockIdx.x;
  if (bid==0 && t==0) {
    const u32 cnt = *(u32*)(ws+W_ATOM+1);
    const float cap = (float)cnt / (float)S_N;
    out[OUT_SC+3] = cap;
    ((int*)(ws+W_FLAG))[0] = (cap > 0.85f) ? 1 : 0;
  }
  const float step = (float)(*stepp);
  const float agemax = __uint_as_float(*(u32*)(ws+W_ATOM+0));
  const float dnm = agemax + 1e-6f;
  const float* n2 = ws+W_NORM2;
  const int base = bid*512;
  u64 best = 0;
  #pragma unroll
  for (int i=0;i<2;i++) {
    const int s = base + t + i*256;
    const float age = fmaxf(step - at_in[s], 0.0f);
    const float q = age/dnm;
    const float nr = sqrtf(n2[s]);
    const float sc = q + (1.0f - sigm(nr));
    const u64 key = ((u64)__float_as_uint(sc)<<32) | (u64)(0xFFFFFFFFu - (u32)s);
    best = (key>best)?key:best;
  }
  red[t]=best; __syncthreads();
  for (int o=128;o>0;o>>=1){ if(t<o){ u64 a=red[t],b2=red[t+o]; red[t]=(a>b2)?a:b2; } __syncthreads(); }
  if (t==0) atomicMax((u64*)(ws+W_ATOM+2), red[0]);
}

// ---------------- K3m: [bid<256] at copy + erase_scores + es argmax; [bid>=256] top3 merge ----------------
__device__ __forceinline__ void ins3(float v, int idx, float* V, int* I){
  if ( (v>V[0]) || (v==V[0] && idx<I[0]) ) { V[2]=V[1];I[2]=I[1]; V[1]=V[0];I[1]=I[0]; V[0]=v;I[0]=idx; }
  else if ( (v>V[1]) || (v==V[1] && idx<I[1]) ) { V[2]=V[1];I[2]=I[1]; V[1]=v;I[1]=idx; }
  else if ( (v>V[2]) || (v==V[2] && idx<I[2]) ) { V[2]=v;I[2]=idx; }
}

__global__ __launch_bounds__(256) void k3m(
    const float* __restrict__ at_in, const int* __restrict__ stepp,
    const float* __restrict__ lru_w, const float* __restrict__ lru_b,
    const float* __restrict__ eg_w, const float* __restrict__ eg_b,
    const float* __restrict__ conf_b,
    float* __restrict__ ws, float* __restrict__ out)
{
  __shared__ u64 red[256];
  __shared__ float lv[768];
  __shared__ int   li[768];
  __shared__ float lm[256];
  const int t=threadIdx.x, bid=blockIdx.x;
  const u64 vk = *(u64*)(ws+W_ATOM+2);
  const int victim = (int)(0xFFFFFFFFu - (u32)(vk & 0xFFFFFFFFull));
  const int oc = ((int*)(ws+W_FLAG))[0];
  if (bid < 256) {
    if (bid==0 && t==0) ((int*)(ws+W_FLAG))[1] = victim;
    const float step = (float)(*stepp);
    float* at_out = out + OUT_AT;
    float* es_out = out + OUT_ES;
    const float* cer = ws+W_CER;
    u64 best=0;
    const int base=bid*512;
    for (int i=0;i<2;i++){
      const int s = base + t + i*256;
      const float a = at_in[s];
      const bool isv = oc && (s==victim);
      const float av = isv ? -99999.0f : a;
      at_out[s] = av;
      const float x = (step - av)/1000.0f;
      float lsum = 0.0f;
      #pragma unroll
      for (int j=0;j<32;j++) lsum += eg_w[j]*fmaxf(lru_w[j]*x + lru_b[j], 0.0f);
      float ce;
      if (isv) { ce=0.0f; for (int j=0;j<32;j++) ce += eg_w[32+j]*sigm(conf_b[j]); }
      else ce = cer[s];
      const float es = sigm(lsum + ce + eg_b[0]);
      es_out[s] = es;
      const u64 key = ((u64)__float_as_uint(es)<<32) | (u64)(0xFFFFFFFFu - (u32)s);
      best = (key>best)?key:best;
    }
    red[t]=best; __syncthreads();
    for (int o=128;o>0;o>>=1){ if(t<o){ u64 a=red[t],b2=red[t+o]; red[t]=(a>b2)?a:b2; } __syncthreads(); }
    if (t==0) atomicMax((u64*)(ws+W_ATOM+4), red[0]);
  } else {
    const int b = bid - 256;
    const float* t4v = ws + W_T4V + (long)b*8192;
    const int*   t4i = (const int*)(ws + W_T4I) + (long)b*8192;
    float V[3] = {-2,-2,-2}; int I[3] = {0,0,0};
    float mx = -2.0f;
    for (int c=t; c<8192; c+=256) {
      const float v = t4v[c];
      const int idx = t4i[c];
      if ((c&3)==0) mx = fmaxf(mx, v);        // max_sim uses pre-erase sims incl. victim
      if (oc && idx==victim) continue;        // post-erase sims2: victim row becomes 0
      ins3(v, idx, V, I);
    }
    lv[t*3]=V[0]; lv[t*3+1]=V[1]; lv[t*3+2]=V[2];
    li[t*3]=I[0]; li[t*3+1]=I[1]; li[t*3+2]=I[2];
    lm[t]=mx;
    __syncthreads();
    for (int off=128; off>=1; off>>=1){
      if (t<off){
        float A0=lv[t*3],A1=lv[t*3+1],A2=lv[t*3+2];
        int   B0=li[t*3],B1=li[t*3+1],B2=li[t*3+2];
        float AV[3]={A0,A1,A2}; int AI[3]={B0,B1,B2};
        ins3(lv[(t+off)*3+0], li[(t+off)*3+0], AV, AI);
        ins3(lv[(t+off)*3+1], li[(t+off)*3+1], AV, AI);
        ins3(lv[(t+off)*3+2], li[(t+off)*3+2], AV, AI);
        lv[t*3]=AV[0]; lv[t*3+1]=AV[1]; lv[t*3+2]=AV[2];
        li[t*3]=AI[0]; li[t*3+1]=AI[1]; li[t*3+2]=AI[2];
        lm[t]=fmaxf(lm[t], lm[t+off]);
      }
      __syncthreads();
    }
    if (t==0) {
      float FV[3]={lv[0],lv[1],lv[2]}; int FI[3]={li[0],li[1],li[2]};
      if (oc) ins3(0.0f, victim, FV, FI);     // sims2[b][victim] == 0 exactly
      for (int p=0;p<3;p++){ (ws+W_T3V)[b*3+p]=FV[p]; ((int*)(ws+W_T3I))[b*3+p]=FI[p]; }
      (ws+W_MAXS)[b]=lm[0];
    }
  }
}

// ---------------- K4: drift-detect/strength MLPs + candidates; block 96 = scalar stats/flags ----------------
__global__ __launch_bounds__(256) void k4(
    const float* __restrict__ mem, const float* __restrict__ nc,
    const float* __restrict__ dd_w1, const float* __restrict__ dd_b1,
    const float* __restrict__ dd_w2, const float* __restrict__ dd_b2,
    const float* __restrict__ ds_w1, const float* __restrict__ ds_b1,
    const float* __restrict__ ds_w2, const float* __restrict__ ds_b2,
    float* __restrict__ ws, float* __restrict__ out)
{
  const int bid = blockIdx.x, t = threadIdx.x;
  const int oc = ((int*)(ws+W_FLAG))[0];
  const int victim = ((int*)(ws+W_FLAG))[1];
  if (bid == 96) {
    if (t==0) {
      const float sm = (ws+W_ATOM)[6] / 32.0f;
      float nsum=0.0f, rsum=0.0f, csum=0.0f;
      for (int b2=0;b2<32;b2++){
        const float ms = (ws+W_MAXS)[b2];
        nsum += (1.0f-ms)/2.0f;
        rsum += sigm(ms);
      }
      for (int c=0;c<96;c++){
        const float v=(ws+W_T3V)[c];
        if (v>0.7f && v<0.99f) csum += 1.0f;
      }
      const float novm = nsum/32.0f;
      out[OUT_SC+0]=sm;
      out[OUT_SC+1]=novm;
      out[OUT_SC+2]=rsum/32.0f;
      out[OUT_SC+4]=csum;
      ((int*)(ws+W_FLAG))[2] = (sm>0.35f && novm>0.4f) ? 1 : 0;
      const u64 ek = *(u64*)(ws+W_ATOM+4);
      const int esidx = (int)(0xFFFFFFFFu - (u32)(ek & 0xFFFFFFFFull));
      ((int*)(ws+W_FLAG))[3] = oc ? victim : esidx;
    }
    return;
  }
  __shared__ __align__(16) float sp[1024];
  __shared__ __align__(16) float sh[256];
  __shared__ float red[256];
  const int b = bid/3;
  const int oi = ((int*)(ws+W_T3I))[bid];
  const float tv = (ws+W_T3V)[bid];
  const bool zold = oc && (oi==victim);   // gather from post-erase mem
  for (int i=t;i<1024;i+=256)
    sp[i] = (i<512) ? nc[b*512+i] : (zold ? 0.0f : mem[(long)oi*512 + (i-512)]);
  __syncthreads();
  const float4* sp4 = (const float4*)sp;
  {
    const float4* wr = (const float4*)(dd_w1 + (long)t*1024);
    float a = dd_b1[t];
    #pragma unroll 4
    for (int k=0;k<256;k++){ float4 w=wr[k], s=sp4[k]; a += w.x*s.x+w.y*s.y+w.z*s.z+w.w*s.w; }
    sh[t]=fmaxf(a,0.0f);
  }
  __syncthreads();
  red[t]=sh[t]*dd_w2[t]; __syncthreads();
  for (int o=128;o>0;o>>=1){ if(t<o) red[t]+=red[t+o]; __syncthreads(); }
  const float prob = sigm(red[0]+dd_b2[0]);
  __syncthreads();
  {
    const float4* wr = (const float4*)(ds_w1 + (long)t*1024);
    float a = ds_b1[t];
    #pragma unroll 4
    for (int k=0;k<256;k++){ float4 w=wr[k], s=sp4[k]; a += w.x*s.x+w.y*s.y+w.z*s.z+w.w*s.w; }
    sh[t]=fmaxf(a,0.0f);
  }
  __syncthreads();
  red[t]=sh[t]*ds_w2[t]; __syncthreads();
  for (int o=128;o>0;o>>=1){ if(t<o) red[t]+=red[t+o]; __syncthreads(); }
  const float sstr = sigm(red[0]+ds_b2[0]);
  if (t==0) ((int*)(ws+W_ACT))[bid] = ((tv>0.7f) && (tv<0.99f) && (prob>0.5f)) ? 1 : 0;
  for (int k=t;k<512;k+=256){
    const float nw=sp[k], od=sp[512+k];
    const float avg=(nw+od)/2.0f;
    (ws+W_CN)[(long)bid*512+k] = (1.0f-sstr)*nw + sstr*avg;
    (ws+W_CO)[(long)bid*512+k] = (1.0f-sstr)*od + sstr*avg;
  }
}

// ---------------- K5: sequential finale (erase, drift scatter, store, change/ema/decay) ----------------
__global__ __launch_bounds__(256) void k5(
    const float* __restrict__ mem, const float* __restrict__ nc,
    const float* __restrict__ decay_in, const float* __restrict__ ema_in,
    const int* __restrict__ stepp,
    float* __restrict__ ws, float* __restrict__ out)
{
  __shared__ int rows[256];
  __shared__ int nrows_s;
  __shared__ float red[256];
  const int t=threadIdx.x;
  const int oc=((int*)(ws+W_FLAG))[0];
  const int victim=((int*)(ws+W_FLAG))[1];
  const int should=((int*)(ws+W_FLAG))[2];
  const int widx=((int*)(ws+W_FLAG))[3];
  const int* act=(const int*)(ws+W_ACT);
  const int* t3i=(const int*)(ws+W_T3I);
  const float step=(float)(*stepp);
  float* at_out = out+OUT_AT;
  // 1. emergency erase (at[victim] already fixed by k3m)
  if (oc) { for (int k=t;k<512;k+=256) out[(long)victim*512+k]=0.0f; }
  __threadfence(); __syncthreads();
  // 2. sequential masked drift scatter
  for (int i=0;i<96;i++){
    if (act[i]) {
      const long s=t3i[i];
      for (int k=t;k<512;k+=256) out[s*512+k]=(ws+W_CO)[(long)i*512+k];
    }
  }
  int dn_src=-1;
  for (int i=0;i<3;i++) if (act[i]) dn_src=i;   // drifted_new[0] = last active of b==0
  __threadfence(); __syncthreads();
  // 3. conditional store
  if (should) {
    for (int k=t;k<512;k+=256)
      out[(long)widx*512+k] = (dn_src>=0)? (ws+W_CN)[(long)dn_src*512+k] : nc[k];
    if (t==0) at_out[widx]=step;
  }
  __threadfence(); __syncthreads();
  // 4. change = mean |mem_final - mem0| : only changed rows contribute
  if (t==0){
    int n=0;
    if (oc) rows[n++]=victim;
    for (int i=0;i<96;i++) if (act[i]) {
      const int s=t3i[i]; bool dup=false;
      for (int j=0;j<n;j++) if (rows[j]==s) dup=true;
      if (!dup) rows[n++]=s;
    }
    if (should) {
      bool dup=false;
      for (int j=0;j<n;j++) if (rows[j]==widx) dup=true;
      if (!dup) rows[n++]=widx;
    }
    nrows_s=n;
  }
  __syncthreads();
  float part=0.0f;
  for (int ri=0;ri<nrows_s;ri++){
    const long base=(long)rows[ri]*512;
    for (int k=t;k<512;k+=256) part += fabsf(out[base+k]-mem[base+k]);
  }
  red[t]=part; __syncthreads();
  for (int o=128;o>0;o>>=1){ if(t<o) red[t]+=red[t+o]; __syncthreads(); }
  if (t==0){
    const float change = red[0]/67108864.0f;
    const float ema = 0.9f*ema_in[0] + 0.1f*change;
    const float adj = (ema>0.1f)? -0.005f : 0.005f;
    const float dec = fminf(fmaxf(decay_in[0]+adj,0.01f),0.2f);
    out[OUT_SC+5]=dec;
    out[OUT_SC+6]=ema;
  }
}

extern "C" void kernel_launch(void* const* d_in, const int* in_sizes, int n_in,
                              void* d_out, int out_size, void* d_ws, size_t ws_size,
                              hipStream_t stream) {
  const float* nc     = (const float*)d_in[0];
  const float* query  = (const float*)d_in[1];
  const float* mem    = (const float*)d_in[2];
  const float* at_in  = (const float*)d_in[3];
  const float* rel_w1 = (const float*)d_in[4];
  const float* rel_b1 = (const float*)d_in[5];
  const float* rel_g  = (const float*)d_in[6];
  const float* rel_bb = (const float*)d_in[7];
  const float* rel_w2 = (const float*)d_in[8];
  const float* rel_b2 = (const float*)d_in[9];
  const float* nov_w  = (const float*)d_in[10];
  const float* nov_b  = (const float*)d_in[11];
  const float* gate_w = (const float*)d_in[12];
  const float* gate_b = (const float*)d_in[13];
  const float* lru_w  = (const float*)d_in[14];
  const float* lru_b  = (const float*)d_in[15];
  const float* conf_w = (const float*)d_in[16];
  const float* conf_b = (const float*)d_in[17];
  const float* eg_w   = (const float*)d_in[18];
  const float* eg_b   = (const float*)d_in[19];
  const float* dd_w1  = (const float*)d_in[20];
  const float* dd_b1  = (const float*)d_in[21];
  const float* dd_w2  = (const float*)d_in[22];
  const float* dd_b2  = (const float*)d_in[23];
  const float* ds_w1  = (const float*)d_in[24];
  const float* ds_b1  = (const float*)d_in[25];
  const float* ds_w2  = (const float*)d_in[26];
  const float* ds_b2  = (const float*)d_in[27];
  const float* decay  = (const float*)d_in[28];
  const float* ema    = (const float*)d_in[29];
  const int*   stepp  = (const int*)d_in[30];
  float* out = (float*)d_out;
  float* ws  = (float*)d_ws;

  hipMemsetAsync((char*)d_ws + (size_t)W_ATOM*4, 0, 32, stream);

  k0 <<<dim3(256), dim3(256), 0, stream>>>(nc, query, at_in, rel_w1, rel_b1, rel_g, rel_bb,
                                           rel_w2, rel_b2, nov_w, nov_b, gate_w, gate_b,
                                           conf_w, stepp, ws);
  k1 <<<dim3(2048), dim3(256), 0, stream>>>(mem, conf_b, eg_w, out, ws);
  kv2<<<dim3(256), dim3(256), 0, stream>>>(at_in, stepp, ws, out);
  k3m<<<dim3(288), dim3(256), 0, stream>>>(at_in, stepp, lru_w, lru_b, eg_w, eg_b, conf_b, ws, out);
  k4 <<<dim3(97),  dim3(256), 0, stream>>>(mem, nc, dd_w1, dd_b1, dd_w2, dd_b2,
                                           ds_w1, ds_b1, ds_w2, ds_b2, ws, out);
  k5 <<<dim3(1),   dim3(256), 0, stream>>>(mem, nc, decay, ema, stepp, ws, out);
}